// Round 5
// baseline (453.842 us; speedup 1.0000x reference)
//
#include <hip/hip_runtime.h>

#define STEPS   200
#define NT      199
#define BATCH   512
#define IN_DIM  784
#define OUT_DIM 10
#define NCHUNK  16
#define CHUNK   49                  // IN_DIM / NCHUNK
#define WSTR    12                  // weight LDS row stride (48 B, 16 B aligned)
#define DROW    200                 // padded t-stride in drive LDS (800 B, 16 B aligned)
#define NC2     8                   // merged partial slots

// One block per batch element; 1024 threads = 16 waves, wave c owns input rows
// [49c, 49c+49). Lane owns 4 time bins t0=4*lane (lanes 0..49 active).
// LDS union: phase 1 = weights [784][12] (37.6 KB); after barrier = drive
// partials [8][10][200] (62.5 KB) -> 2 blocks/CU, 32 waves/CU.
__global__ __launch_bounds__(1024, 8) void snn_fwd(
    const float* __restrict__ x,    // [BATCH, IN_DIM, STEPS]
    const float* __restrict__ w,    // [OUT_DIM, IN_DIM]
    float* __restrict__ out)        // [BATCH, OUT_DIM]
{
    __shared__ float smem[NC2 * OUT_DIM * DROW];   // 16000 floats = 62.5 KB
    float* w_lds = smem;                           // [IN_DIM][WSTR]
    float* dlds  = smem;                           // [NC2][OUT_DIM][DROW]

    const int b    = blockIdx.x;
    const int tid  = threadIdx.x;
    const int c    = tid >> 6;      // chunk == wave id, 0..15
    const int lane = tid & 63;
    const int t0   = lane * 4;      // active lanes: t0 < 200
    const bool active = (t0 < STEPS);

    // Stage weights transposed: w_lds[i*WSTR+o] = w[o*IN+i] (coalesced reads).
    for (int idx = tid; idx < IN_DIM * OUT_DIM; idx += 1024) {
        int o = idx / IN_DIM;
        int i = idx - o * IN_DIM;
        w_lds[i * WSTR + o] = w[idx];
    }
    __syncthreads();

    // acc[q][j] = drive partial for t=t0+q, outputs {2j, 2j+1} (packed-fp32-able)
    float2 acc[4][5];
    #pragma unroll
    for (int q = 0; q < 4; ++q)
        #pragma unroll
        for (int j = 0; j < 5; ++j) acc[q][j] = make_float2(0.0f, 0.0f);

    if (active) {
        const float* xb = x + (size_t)b * IN_DIM * STEPS + t0;
        const int i0 = c * CHUNK;

        // Branchless dense accumulate; t=199 lane-tail is computed but lands in
        // a padded LDS slot that the scan never reads.
        #define CONSUME(xv, ii)                                                  \
            do {                                                                 \
                const float4 w0 = *(const float4*)&w_lds[(ii) * WSTR + 0];       \
                const float4 w1 = *(const float4*)&w_lds[(ii) * WSTR + 4];       \
                const float2 w2 = *(const float2*)&w_lds[(ii) * WSTR + 8];       \
                const float2 p0 = make_float2(w0.x, w0.y);                       \
                const float2 p1 = make_float2(w0.z, w0.w);                       \
                const float2 p2 = make_float2(w1.x, w1.y);                       \
                const float2 p3 = make_float2(w1.z, w1.w);                       \
                const float xq[4] = {(xv).x, (xv).y, (xv).z, (xv).w};            \
                _Pragma("unroll")                                                \
                for (int q = 0; q < 4; ++q) {                                    \
                    acc[q][0].x = fmaf(xq[q], p0.x, acc[q][0].x);                \
                    acc[q][0].y = fmaf(xq[q], p0.y, acc[q][0].y);                \
                    acc[q][1].x = fmaf(xq[q], p1.x, acc[q][1].x);                \
                    acc[q][1].y = fmaf(xq[q], p1.y, acc[q][1].y);                \
                    acc[q][2].x = fmaf(xq[q], p2.x, acc[q][2].x);                \
                    acc[q][2].y = fmaf(xq[q], p2.y, acc[q][2].y);                \
                    acc[q][3].x = fmaf(xq[q], p3.x, acc[q][3].x);                \
                    acc[q][3].y = fmaf(xq[q], p3.y, acc[q][3].y);                \
                    acc[q][4].x = fmaf(xq[q], w2.x, acc[q][4].x);                \
                    acc[q][4].y = fmaf(xq[q], w2.y, acc[q][4].y);                \
                }                                                                \
            } while (0)

        // Rolling depth-2 prefetch: row k+1 in flight while consuming row k.
        float4 xa = *(const float4*)(xb + (size_t)i0 * STEPS);
        for (int k = 0; k < CHUNK - 1; ++k) {
            float4 xn = *(const float4*)(xb + (size_t)(i0 + k + 1) * STEPS);
            CONSUME(xa, i0 + k);
            xa = xn;
        }
        CONSUME(xa, i0 + CHUNK - 1);
        #undef CONSUME
    }

    __syncthreads();   // weights dead; smem becomes drive partials

    const int c2 = c >> 1;
    // Even waves write their partials to slot c2 ([o][t] layout, b128, conflict-free).
    if (active && !(c & 1)) {
        #pragma unroll
        for (int j = 0; j < 5; ++j) {
            float4 v0 = make_float4(acc[0][j].x, acc[1][j].x, acc[2][j].x, acc[3][j].x);
            float4 v1 = make_float4(acc[0][j].y, acc[1][j].y, acc[2][j].y, acc[3][j].y);
            *(float4*)&dlds[((c2 * OUT_DIM + 2 * j    ) * DROW) + t0] = v0;
            *(float4*)&dlds[((c2 * OUT_DIM + 2 * j + 1) * DROW) + t0] = v1;
        }
    }
    __syncthreads();
    // Odd waves merge: slot c2 = even_partial + odd_partial (fixed order -> deterministic).
    if (active && (c & 1)) {
        #pragma unroll
        for (int j = 0; j < 5; ++j) {
            float* r0 = &dlds[((c2 * OUT_DIM + 2 * j    ) * DROW) + t0];
            float* r1 = &dlds[((c2 * OUT_DIM + 2 * j + 1) * DROW) + t0];
            float4 v0 = *(float4*)r0;
            float4 v1 = *(float4*)r1;
            v0.x += acc[0][j].x; v0.y += acc[1][j].x; v0.z += acc[2][j].x; v0.w += acc[3][j].x;
            v1.x += acc[0][j].y; v1.y += acc[1][j].y; v1.z += acc[2][j].y; v1.w += acc[3][j].y;
            *(float4*)r0 = v0;
            *(float4*)r1 = v1;
        }
    }
    __syncthreads();

    // LIF scan + first-spike time: one thread per output neuron.
    // Ascending-c2 merge keeps fp summation deterministic.
    if (tid < OUT_DIM) {
        const int o = tid;
        const float a_m = 0.995f;   // 1 - DT/TAU_M
        const float b_m = 0.005f;   // DT/TAU_M
        const float a_s = 0.98f;    // 1 - DT/TAU_S

        float V = 0.0f, I = 0.0f;
        int fst = 0;
        for (int s = 0; s < NT; ++s) {
            float drv = 0.0f;
            #pragma unroll
            for (int k = 0; k < NC2; ++k)
                drv += dlds[(k * OUT_DIM + o) * DROW + s];
            float Vn = a_m * V + b_m * I;   // old I, per reference ordering
            I = a_s * I + drv;
            if (Vn > 1.0f) {
                if (fst == 0) fst = s + 1;  // +1: output zero-padded at t=0
                V = 0.0f;
            } else {
                V = Vn;
            }
        }
        out[b * OUT_DIM + o] = (fst == 0) ? (float)(STEPS - 1) : (float)fst;
    }
}

extern "C" void kernel_launch(void* const* d_in, const int* in_sizes, int n_in,
                              void* d_out, int out_size, void* d_ws, size_t ws_size,
                              hipStream_t stream) {
    const float* x = (const float*)d_in[0];   // [512, 784, 200] fp32
    const float* w = (const float*)d_in[1];   // [10, 784] fp32
    float* out = (float*)d_out;               // [512, 10] fp32
    snn_fwd<<<dim3(BATCH), dim3(1024), 0, stream>>>(x, w, out);
}

// Round 6
// 445.422 us; speedup vs baseline: 1.0189x; 1.0189x over previous
//
#include <hip/hip_runtime.h>

#define STEPS   200
#define NT      199
#define BATCH   512
#define IN_DIM  784
#define OUT_DIM 10
#define NCHUNK  16
#define CHUNK   49                  // IN_DIM / NCHUNK
#define WSTR    12                  // weight LDS row stride (48 B, 16 B aligned)
#define DROW    200                 // t-stride in drive LDS (800 B)
#define NC2     8                   // merged partial slots

// One block per batch element; 1024 threads = 16 waves, wave c owns input rows
// [49c, 49c+49). Lane owns 4 time bins t0=4*lane (lanes 0..49 active).
// __launch_bounds__(1024,4): 1 block/CU, 16 waves/CU, VGPR cap 128 -> NO
// spills (R5's (1024,8)=64-VGPR cap forced inner-loop scratch spills).
// LDS union: phase 1 = weights [784][12] (37.6 KB); after barrier = drive
// partials [8][10][200] (62.5 KB).
__global__ __launch_bounds__(1024, 4) void snn_fwd(
    const float* __restrict__ x,    // [BATCH, IN_DIM, STEPS]
    const float* __restrict__ w,    // [OUT_DIM, IN_DIM]
    float* __restrict__ out)        // [BATCH, OUT_DIM]
{
    __shared__ float smem[NC2 * OUT_DIM * DROW];   // 16000 floats = 62.5 KB
    float* w_lds = smem;                           // [IN_DIM][WSTR]
    float* dlds  = smem;                           // [NC2][OUT_DIM][DROW]

    const int b    = blockIdx.x;
    const int tid  = threadIdx.x;
    const int c    = tid >> 6;      // chunk == wave id, 0..15
    const int lane = tid & 63;
    const int t0   = lane * 4;      // active lanes: t0 < 200
    const bool active = (t0 < STEPS);

    // Stage weights transposed: w_lds[i*WSTR+o] = w[o*IN+i] (coalesced reads).
    for (int idx = tid; idx < IN_DIM * OUT_DIM; idx += 1024) {
        int o = idx / IN_DIM;
        int i = idx - o * IN_DIM;
        w_lds[i * WSTR + o] = w[idx];
    }
    __syncthreads();

    // acc[q][j] = drive partial for t=t0+q, outputs {2j, 2j+1}
    float2 acc[4][5];
    #pragma unroll
    for (int q = 0; q < 4; ++q)
        #pragma unroll
        for (int j = 0; j < 5; ++j) acc[q][j] = make_float2(0.0f, 0.0f);

    if (active) {
        const float* xb = x + (size_t)b * IN_DIM * STEPS + t0;
        const int i0 = c * CHUNK;

        #define LD(ii) (*(const float4*)(xb + (size_t)(ii) * STEPS))
        #define CONSUME(xv, ii)                                                  \
            do {                                                                 \
                const float4 w0 = *(const float4*)&w_lds[(ii) * WSTR + 0];       \
                const float4 w1 = *(const float4*)&w_lds[(ii) * WSTR + 4];       \
                const float2 w2 = *(const float2*)&w_lds[(ii) * WSTR + 8];       \
                const float xq[4] = {(xv).x, (xv).y, (xv).z, (xv).w};            \
                _Pragma("unroll")                                                \
                for (int q = 0; q < 4; ++q) {                                    \
                    acc[q][0].x = fmaf(xq[q], w0.x, acc[q][0].x);                \
                    acc[q][0].y = fmaf(xq[q], w0.y, acc[q][0].y);                \
                    acc[q][1].x = fmaf(xq[q], w0.z, acc[q][1].x);                \
                    acc[q][1].y = fmaf(xq[q], w0.w, acc[q][1].y);                \
                    acc[q][2].x = fmaf(xq[q], w1.x, acc[q][2].x);                \
                    acc[q][2].y = fmaf(xq[q], w1.y, acc[q][2].y);                \
                    acc[q][3].x = fmaf(xq[q], w1.z, acc[q][3].x);                \
                    acc[q][3].y = fmaf(xq[q], w1.w, acc[q][3].y);                \
                    acc[q][4].x = fmaf(xq[q], w2.x, acc[q][4].x);                \
                    acc[q][4].y = fmaf(xq[q], w2.y, acc[q][4].y);                \
                }                                                                \
            } while (0)

        // Depth-4 rolling prefetch: 4 rows in flight while consuming 4.
        // Rows consumed in ascending i -> summation order identical to R5.
        float4 X0 = LD(i0 + 0), X1 = LD(i0 + 1), X2 = LD(i0 + 2), X3 = LD(i0 + 3);
        for (int j = 0; j < 11; ++j) {          // consume rows 4j..4j+3
            const int r = i0 + 4 * j;
            float4 N0 = LD(r + 4), N1 = LD(r + 5), N2 = LD(r + 6), N3 = LD(r + 7);
            CONSUME(X0, r + 0);
            CONSUME(X1, r + 1);
            CONSUME(X2, r + 2);
            CONSUME(X3, r + 3);
            X0 = N0; X1 = N1; X2 = N2; X3 = N3;
        }
        {   // rows 44..47 in X0..X3, then row 48
            float4 L = LD(i0 + 48);
            CONSUME(X0, i0 + 44);
            CONSUME(X1, i0 + 45);
            CONSUME(X2, i0 + 46);
            CONSUME(X3, i0 + 47);
            CONSUME(L,  i0 + 48);
        }
        #undef LD
        #undef CONSUME
    }

    __syncthreads();   // weights dead; smem becomes drive partials

    const int c2 = c >> 1;
    // Even waves write partials to slot c2 ([o][t] layout, b128, conflict-free).
    if (active && !(c & 1)) {
        #pragma unroll
        for (int j = 0; j < 5; ++j) {
            float4 v0 = make_float4(acc[0][j].x, acc[1][j].x, acc[2][j].x, acc[3][j].x);
            float4 v1 = make_float4(acc[0][j].y, acc[1][j].y, acc[2][j].y, acc[3][j].y);
            *(float4*)&dlds[((c2 * OUT_DIM + 2 * j    ) * DROW) + t0] = v0;
            *(float4*)&dlds[((c2 * OUT_DIM + 2 * j + 1) * DROW) + t0] = v1;
        }
    }
    __syncthreads();
    // Odd waves merge: slot c2 = even_partial + odd_partial (fixed order).
    if (active && (c & 1)) {
        #pragma unroll
        for (int j = 0; j < 5; ++j) {
            float* r0 = &dlds[((c2 * OUT_DIM + 2 * j    ) * DROW) + t0];
            float* r1 = &dlds[((c2 * OUT_DIM + 2 * j + 1) * DROW) + t0];
            float4 v0 = *(float4*)r0;
            float4 v1 = *(float4*)r1;
            v0.x += acc[0][j].x; v0.y += acc[1][j].x; v0.z += acc[2][j].x; v0.w += acc[3][j].x;
            v1.x += acc[0][j].y; v1.y += acc[1][j].y; v1.z += acc[2][j].y; v1.w += acc[3][j].y;
            *(float4*)r0 = v0;
            *(float4*)r1 = v1;
        }
    }
    __syncthreads();

    // LIF scan + first-spike time: one thread per output neuron.
    // Ascending-slot merge keeps fp summation deterministic (matches R5).
    if (tid < OUT_DIM) {
        const int o = tid;
        const float a_m = 0.995f;   // 1 - DT/TAU_M
        const float b_m = 0.005f;   // DT/TAU_M
        const float a_s = 0.98f;    // 1 - DT/TAU_S

        float V = 0.0f, I = 0.0f;
        int fst = 0;
        for (int s = 0; s < NT; ++s) {
            float drv = 0.0f;
            #pragma unroll
            for (int k = 0; k < NC2; ++k)
                drv += dlds[(k * OUT_DIM + o) * DROW + s];
            float Vn = a_m * V + b_m * I;   // old I, per reference ordering
            I = a_s * I + drv;
            if (Vn > 1.0f) {
                if (fst == 0) fst = s + 1;  // +1: output zero-padded at t=0
                V = 0.0f;
            } else {
                V = Vn;
            }
        }
        out[b * OUT_DIM + o] = (fst == 0) ? (float)(STEPS - 1) : (float)fst;
    }
}

extern "C" void kernel_launch(void* const* d_in, const int* in_sizes, int n_in,
                              void* d_out, int out_size, void* d_ws, size_t ws_size,
                              hipStream_t stream) {
    const float* x = (const float*)d_in[0];   // [512, 784, 200] fp32
    const float* w = (const float*)d_in[1];   // [10, 784] fp32
    float* out = (float*)d_out;               // [512, 10] fp32
    snn_fwd<<<dim3(BATCH), dim3(1024), 0, stream>>>(x, w, out);
}

// Round 7
// 443.023 us; speedup vs baseline: 1.0244x; 1.0054x over previous
//
#include <hip/hip_runtime.h>

#define STEPS   200
#define NT      199
#define BATCH   512
#define IN_DIM  784
#define OUT_DIM 10
#define NQ      4                   // row quarters (blocks per batch elem)
#define QROWS   196                 // rows per block
#define WROWS   49                  // rows per wave
#define WSTR    12                  // weight LDS row stride (48 B)

// ---------------- Kernel A: drive partials (streaming GEMM) ----------------
// grid = BATCH*NQ, block = 256 (4 waves). Block (b, rq) covers input rows
// [196rq, 196rq+196); wave w rows [49w, 49w+49) of those; lane owns t0=4*lane
// (lanes 0..49 active). Writes partial drive [rq][b][o][t] to workspace.
// LDS 41.4 KB -> 3 blocks/CU; VGPR ~70 (no tight bound) -> all 12 waves fit.
__global__ __launch_bounds__(256) void snn_drive(
    const float* __restrict__ x,      // [BATCH, IN_DIM, STEPS]
    const float* __restrict__ w,      // [OUT_DIM, IN_DIM]
    float* __restrict__ dpart)        // [NQ][BATCH][OUT_DIM][STEPS]
{
    __shared__ float w_lds[QROWS * WSTR];           // 9.4 KB
    __shared__ float pw[4 * OUT_DIM * STEPS];       // 32 KB, [wave][o][t]

    const int bid  = blockIdx.x;
    const int b    = bid >> 2;
    const int rq   = bid & 3;
    const int tid  = threadIdx.x;
    const int wv   = tid >> 6;
    const int lane = tid & 63;
    const int t0   = lane * 4;
    const int rowbase = rq * QROWS;

    // Stage this quarter's weights transposed (coalesced global reads).
    for (int idx = tid; idx < QROWS * OUT_DIM; idx += 256) {
        int o = idx / QROWS;
        int i = idx - o * QROWS;
        w_lds[i * WSTR + o] = w[o * IN_DIM + rowbase + i];
    }
    __syncthreads();

    float2 acc[4][5];                // [t-quad][o-pair]
    #pragma unroll
    for (int q = 0; q < 4; ++q)
        #pragma unroll
        for (int j = 0; j < 5; ++j) acc[q][j] = make_float2(0.0f, 0.0f);

    if (t0 < STEPS) {
        const float* xb = x + (size_t)b * IN_DIM * STEPS + (size_t)rowbase * STEPS + t0;
        const int i0 = wv * WROWS;   // local row base within quarter

        #define LD(r) (*(const float4*)(xb + (size_t)(r) * STEPS))
        #define CONSUME(xv, r)                                                   \
            do {                                                                 \
                const float4 w0 = *(const float4*)&w_lds[(r) * WSTR + 0];        \
                const float4 w1 = *(const float4*)&w_lds[(r) * WSTR + 4];        \
                const float2 w2 = *(const float2*)&w_lds[(r) * WSTR + 8];        \
                const float xq[4] = {(xv).x, (xv).y, (xv).z, (xv).w};            \
                _Pragma("unroll")                                                \
                for (int q = 0; q < 4; ++q) {                                    \
                    acc[q][0].x = fmaf(xq[q], w0.x, acc[q][0].x);                \
                    acc[q][0].y = fmaf(xq[q], w0.y, acc[q][0].y);                \
                    acc[q][1].x = fmaf(xq[q], w0.z, acc[q][1].x);                \
                    acc[q][1].y = fmaf(xq[q], w0.w, acc[q][1].y);                \
                    acc[q][2].x = fmaf(xq[q], w1.x, acc[q][2].x);                \
                    acc[q][2].y = fmaf(xq[q], w1.y, acc[q][2].y);                \
                    acc[q][3].x = fmaf(xq[q], w1.z, acc[q][3].x);                \
                    acc[q][3].y = fmaf(xq[q], w1.w, acc[q][3].y);                \
                    acc[q][4].x = fmaf(xq[q], w2.x, acc[q][4].x);                \
                    acc[q][4].y = fmaf(xq[q], w2.y, acc[q][4].y);                \
                }                                                                \
            } while (0)

        // Depth-4 rolling prefetch over 49 rows, ascending i (deterministic).
        float4 X0 = LD(i0 + 0), X1 = LD(i0 + 1), X2 = LD(i0 + 2), X3 = LD(i0 + 3);
        for (int j = 0; j < 11; ++j) {
            const int r = i0 + 4 * j;
            float4 N0 = LD(r + 4), N1 = LD(r + 5), N2 = LD(r + 6), N3 = LD(r + 7);
            CONSUME(X0, r + 0);
            CONSUME(X1, r + 1);
            CONSUME(X2, r + 2);
            CONSUME(X3, r + 3);
            X0 = N0; X1 = N1; X2 = N2; X3 = N3;
        }
        {
            float4 L = LD(i0 + 48);
            CONSUME(X0, i0 + 44);
            CONSUME(X1, i0 + 45);
            CONSUME(X2, i0 + 46);
            CONSUME(X3, i0 + 47);
            CONSUME(L,  i0 + 48);
        }
        #undef LD
        #undef CONSUME

        // Wave partial -> LDS [wv][o][t], b128 conflict-free.
        #pragma unroll
        for (int j = 0; j < 5; ++j) {
            float4 v0 = make_float4(acc[0][j].x, acc[1][j].x, acc[2][j].x, acc[3][j].x);
            float4 v1 = make_float4(acc[0][j].y, acc[1][j].y, acc[2][j].y, acc[3][j].y);
            *(float4*)&pw[(wv * OUT_DIM + 2 * j    ) * STEPS + t0] = v0;
            *(float4*)&pw[(wv * OUT_DIM + 2 * j + 1) * STEPS + t0] = v1;
        }
    }
    __syncthreads();

    // Merge 4 wave-partials (ascending wave = ascending rows) and store.
    float* dst = dpart + ((size_t)(rq * BATCH + b)) * OUT_DIM * STEPS;
    const float4* p0 = (const float4*)&pw[0 * OUT_DIM * STEPS];
    const float4* p1 = (const float4*)&pw[1 * OUT_DIM * STEPS];
    const float4* p2 = (const float4*)&pw[2 * OUT_DIM * STEPS];
    const float4* p3 = (const float4*)&pw[3 * OUT_DIM * STEPS];
    for (int s = tid; s < OUT_DIM * STEPS / 4; s += 256) {
        float4 a = p0[s], c = p1[s], d = p2[s], e = p3[s];
        float4 v;
        v.x = ((a.x + c.x) + d.x) + e.x;
        v.y = ((a.y + c.y) + d.y) + e.y;
        v.z = ((a.z + c.z) + d.z) + e.z;
        v.w = ((a.w + c.w) + d.w) + e.w;
        ((float4*)dst)[s] = v;
    }
}

// ---------------- Kernel B: quarter-merge + LIF scan ----------------
// grid = BATCH, block = 64 (1 wave). Sums the 4 quarter-partials into LDS
// (fixed ascending rq -> deterministic), then lanes 0..9 run the serial scan.
__global__ __launch_bounds__(64) void snn_scan(
    const float* __restrict__ dpart,  // [NQ][BATCH][OUT_DIM][STEPS]
    float* __restrict__ out)          // [BATCH, OUT_DIM]
{
    __shared__ float ds[OUT_DIM * STEPS];   // 8 KB, [o][t]

    const int b    = blockIdx.x;
    const int lane = threadIdx.x;
    const size_t qstride4 = (size_t)BATCH * OUT_DIM * STEPS / 4;   // in float4s
    const float4* base = (const float4*)(dpart + (size_t)b * OUT_DIM * STEPS);

    for (int s = lane; s < OUT_DIM * STEPS / 4; s += 64) {
        float4 a = base[s];
        float4 c = base[s + qstride4];
        float4 d = base[s + 2 * qstride4];
        float4 e = base[s + 3 * qstride4];
        float4 v;
        v.x = ((a.x + c.x) + d.x) + e.x;
        v.y = ((a.y + c.y) + d.y) + e.y;
        v.z = ((a.z + c.z) + d.z) + e.z;
        v.w = ((a.w + c.w) + d.w) + e.w;
        ((float4*)ds)[s] = v;
    }
    __syncthreads();

    if (lane < OUT_DIM) {
        const int o = lane;
        const float* dso = &ds[o * STEPS];
        const float a_m = 0.995f;   // 1 - DT/TAU_M
        const float b_m = 0.005f;   // DT/TAU_M
        const float a_s = 0.98f;    // 1 - DT/TAU_S

        float V = 0.0f, I = 0.0f;
        int fst = 0;
        for (int s = 0; s < NT; ++s) {
            float drv = dso[s];
            float Vn = a_m * V + b_m * I;   // old I, per reference ordering
            I = a_s * I + drv;
            if (Vn > 1.0f) {
                if (fst == 0) fst = s + 1;  // +1: output zero-padded at t=0
                V = 0.0f;
            } else {
                V = Vn;
            }
        }
        out[b * OUT_DIM + o] = (fst == 0) ? (float)(STEPS - 1) : (float)fst;
    }
}

extern "C" void kernel_launch(void* const* d_in, const int* in_sizes, int n_in,
                              void* d_out, int out_size, void* d_ws, size_t ws_size,
                              hipStream_t stream) {
    const float* x = (const float*)d_in[0];   // [512, 784, 200] fp32
    const float* w = (const float*)d_in[1];   // [10, 784] fp32
    float* out   = (float*)d_out;             // [512, 10] fp32
    float* dpart = (float*)d_ws;              // [4][512][10][200] = 16.4 MB

    snn_drive<<<dim3(BATCH * NQ), dim3(256), 0, stream>>>(x, w, dpart);
    snn_scan <<<dim3(BATCH),      dim3(64),  0, stream>>>(dpart, out);
}